// Round 20
// baseline (78.575 us; speedup 1.0000x reference)
//
#include <hip/hip_runtime.h>

typedef short bf16x8 __attribute__((ext_vector_type(8)));
typedef float f32x4 __attribute__((ext_vector_type(4)));
typedef float f32x16 __attribute__((ext_vector_type(16)));
typedef unsigned short u16;
typedef unsigned int u32;

#define MFMA_BF16 __builtin_amdgcn_mfma_f32_16x16x32_bf16
#define MFMA32 __builtin_amdgcn_mfma_f32_32x32x16_bf16

static __device__ __forceinline__ u16 f2bf(float f) {
  union { float f; unsigned u; } v; v.f = f;
  return (u16)((v.u + 0x7FFFu + ((v.u >> 16) & 1u)) >> 16);  // RNE
}
static __device__ __forceinline__ u32 cvtpk(float lo, float hi) {
  u32 r;
  asm("v_cvt_pk_bf16_f32 %0, %1, %2" : "=v"(r) : "v"(lo), "v"(hi));
  return r;  // lo -> bits[15:0], hi -> bits[31:16]
}
static __device__ __forceinline__ bf16x8 cvt8(uint4 p, uint4 q) {  // 8 fp32 (raw bits) -> bf16x8
  union { u32 w[4]; bf16x8 b; } r;
  r.w[0] = cvtpk(__uint_as_float(p.x), __uint_as_float(p.y));
  r.w[1] = cvtpk(__uint_as_float(p.z), __uint_as_float(p.w));
  r.w[2] = cvtpk(__uint_as_float(q.x), __uint_as_float(q.y));
  r.w[3] = cvtpk(__uint_as_float(q.z), __uint_as_float(q.w));
  return r.b;
}
static __device__ __forceinline__ float xhalf(float x) { return __shfl_xor(x, 32); }
static __device__ __forceinline__ u32 xhalfu(u32 x) { return (u32)__shfl_xor((int)x, 32); }

// async global -> LDS, 16B per lane; LDS dest = wave-uniform base + lane*16
static __device__ __forceinline__ void gload16(const void* g, void* l) {
  __builtin_amdgcn_global_load_lds(
      (const __attribute__((address_space(1))) u32*)g,
      (__attribute__((address_space(3))) u32*)l, 16, 0, 0);
}

// ---------------- Kernel 0: W -> Wt[192][1024] bf16; Q gets 1/sqrt(64)*log2(e) folded in
__global__ __launch_bounds__(256) void wt_kernel(const float* __restrict__ Wq,
                                                 const float* __restrict__ Wk,
                                                 const float* __restrict__ Wv,
                                                 u16* __restrict__ Wt) {
  const int nrow = blockIdx.x;               // 0..191
  const int m = nrow >> 6, n = nrow & 63;
  const float* W = (m == 0) ? Wq : ((m == 1) ? Wk : Wv);
  const float s = (m == 0) ? 0.125f * 1.44269504f : 1.0f;  // scores in base-2 units
  for (int k = threadIdx.x; k < 1024; k += 256)
    Wt[(size_t)nrow * 1024 + k] = f2bf(W[(size_t)k * 64 + n] * s);
}

// ---------------- Kernel 1: QKV projection via global_load_lds (qkv6, proven ~30us).
// V is written UNIT-TILED: Vt[tile = tok/32][d = 0..63][key_in_unit = 0..31]
__global__ __launch_bounds__(256) void qkv6(const float* __restrict__ x,
                                            const u16* __restrict__ Wt,
                                            u16* __restrict__ Qb,
                                            u16* __restrict__ Kb,
                                            u16* __restrict__ Vt) {
  __shared__ __align__(16) char sh[2][32 * 1024];
  const int w = threadIdx.x >> 6, l = threadIdx.x & 63;
  const int lane16 = l & 15, laneHi = l >> 4;
  const int r0 = blockIdx.x * 32;
  const int nt0 = w * 3;

  const f32x4 fzero = {0.f, 0.f, 0.f, 0.f};
  f32x4 acc0 = fzero, acc1 = fzero, acc2 = fzero;   // m0 x {nt0,nt0+1,nt0+2}
  f32x4 acc3 = fzero, acc4 = fzero, acc5 = fzero;   // m1 x {nt0,nt0+1,nt0+2}

  auto stage = [&](int buf, int s) {
    char* base = &sh[buf][0];
    const int k0 = s * 64;
    if (w < 3) {
#pragma unroll
      for (int ii = 0; ii < 8; ++ii) {
        const int nt = w * 4 + (ii >> 1), kh = ii & 1;
        const u16* g = Wt + (size_t)(nt * 16 + lane16) * 1024 + k0 + kh * 32 + laneHi * 8;
        gload16(g, base + (nt * 2 + kh) * 1024);
      }
    } else {
#pragma unroll
      for (int ii = 0; ii < 8; ++ii) {
        const int m = ii >> 2, kh = (ii >> 1) & 1, p = ii & 1;
        const float* g = x + (size_t)(r0 + m * 16 + lane16) * 1024 + k0 + kh * 32 + laneHi * 8 + p * 4;
        gload16(g, base + (24 + ii) * 1024);
      }
    }
  };

  auto comp = [&](int buf) {
    const char* base = &sh[buf][0] + (size_t)l * 16;
    bf16x8 b00 = *(const bf16x8*)(base + ((nt0 + 0) * 2 + 0) * 1024);
    bf16x8 b01 = *(const bf16x8*)(base + ((nt0 + 0) * 2 + 1) * 1024);
    bf16x8 b10 = *(const bf16x8*)(base + ((nt0 + 1) * 2 + 0) * 1024);
    bf16x8 b11 = *(const bf16x8*)(base + ((nt0 + 1) * 2 + 1) * 1024);
    bf16x8 b20 = *(const bf16x8*)(base + ((nt0 + 2) * 2 + 0) * 1024);
    bf16x8 b21 = *(const bf16x8*)(base + ((nt0 + 2) * 2 + 1) * 1024);
    uint4 x00a = *(const uint4*)(base + 24 * 1024);
    uint4 x00b = *(const uint4*)(base + 25 * 1024);
    uint4 x01a = *(const uint4*)(base + 26 * 1024);
    uint4 x01b = *(const uint4*)(base + 27 * 1024);
    uint4 x10a = *(const uint4*)(base + 28 * 1024);
    uint4 x10b = *(const uint4*)(base + 29 * 1024);
    uint4 x11a = *(const uint4*)(base + 30 * 1024);
    uint4 x11b = *(const uint4*)(base + 31 * 1024);
    bf16x8 a00 = cvt8(x00a, x00b);   // m0, k 0-31 slice
    bf16x8 a01 = cvt8(x01a, x01b);   // m0, k 32-63
    bf16x8 a10 = cvt8(x10a, x10b);   // m1, k 0-31
    bf16x8 a11 = cvt8(x11a, x11b);   // m1, k 32-63
    acc0 = MFMA_BF16(a00, b00, acc0, 0, 0, 0);
    acc0 = MFMA_BF16(a01, b01, acc0, 0, 0, 0);
    acc1 = MFMA_BF16(a00, b10, acc1, 0, 0, 0);
    acc1 = MFMA_BF16(a01, b11, acc1, 0, 0, 0);
    acc2 = MFMA_BF16(a00, b20, acc2, 0, 0, 0);
    acc2 = MFMA_BF16(a01, b21, acc2, 0, 0, 0);
    acc3 = MFMA_BF16(a10, b00, acc3, 0, 0, 0);
    acc3 = MFMA_BF16(a11, b01, acc3, 0, 0, 0);
    acc4 = MFMA_BF16(a10, b10, acc4, 0, 0, 0);
    acc4 = MFMA_BF16(a11, b11, acc4, 0, 0, 0);
    acc5 = MFMA_BF16(a10, b20, acc5, 0, 0, 0);
    acc5 = MFMA_BF16(a11, b21, acc5, 0, 0, 0);
  };

  stage(0, 0);
  __syncthreads();
#pragma unroll 1
  for (int s = 0; s < 16; ++s) {
    if (s + 1 < 16) stage((s + 1) & 1, s + 1);   // async prefetch, no VGPR cost
    comp(s & 1);
    __syncthreads();                              // drains vmcnt; buf swap safe
  }

#define ST(AC, m, i)                                                        \
  {                                                                         \
    const int nt = nt0 + (i);                                               \
    if (nt < 4) {                                                           \
      _Pragma("unroll")                                                     \
      for (int r = 0; r < 4; ++r)                                           \
        Qb[(size_t)(r0 + (m) * 16 + laneHi * 4 + r) * 64 + nt * 16 + lane16] = f2bf(AC[r]); \
    } else if (nt < 8) {                                                    \
      _Pragma("unroll")                                                     \
      for (int r = 0; r < 4; ++r)                                           \
        Kb[(size_t)(r0 + (m) * 16 + laneHi * 4 + r) * 64 + (nt - 4) * 16 + lane16] = f2bf(AC[r]); \
    } else {                                                                \
      const int d = (nt - 8) * 16 + lane16;                                 \
      uint2 v;                                                              \
      v.x = cvtpk(AC[0], AC[1]);                                            \
      v.y = cvtpk(AC[2], AC[3]);                                            \
      *(uint2*)(Vt + ((size_t)(r0 >> 5) * 64 + d) * 32 + (m) * 16 + laneHi * 4) = v; \
    }                                                                       \
  }

  ST(acc0, 0, 0) ST(acc1, 0, 1) ST(acc2, 0, 2)
  ST(acc3, 1, 0) ST(acc4, 1, 1) ST(acc5, 1, 2)
}

// ---------------- Kernel 2: SHARED-KV paired-tile flash attention.
// 256 blocks x 8 waves. Block owns tiles (tA=p, tB=127-p) of one batch: total
// steps = (tA+1)+(tB+1) = 130 = CONSTANT -> perfect per-CU balance at 1 block/CU
// (8 waves = 2/SIMD, same as attn9). Each wave takes units u = w, w+8, ... of
// the union range [0,tB]; one K/V load serves BOTH tiles (A-step when u<=tA)
// -> ~26% less KV traffic at identical compute. Tree max/sum (depth 4).
// Two hierarchical 8->4->1 combine passes (tile A then B).
__global__ __launch_bounds__(512) void attn13(const u16* __restrict__ Qb,
                                              const u16* __restrict__ Kb,
                                              const u16* __restrict__ Vt,
                                              float* __restrict__ out) {
  __shared__ float shC[4][64][37];
  __shared__ __align__(16) float shT[32][68];

  const int tid = threadIdx.x, w = tid >> 6, l = tid & 63;
  const int q = l & 31, hi = l >> 5;
  const bool isHi = hi != 0;
  const int b = blockIdx.x & 3;
  const int tp = blockIdx.x >> 2;                  // 0..63
  const int tA = tp, tB = 127 - tp;
  const int q0A = tA * 32, q0B = tB * 32, bT = b * 4096;

  const u16* qpA = Qb + (size_t)(bT + q0A + q) * 64 + 8 * hi;
  const bf16x8 qA0 = *(const bf16x8*)(qpA);
  const bf16x8 qA1 = *(const bf16x8*)(qpA + 16);
  const bf16x8 qA2 = *(const bf16x8*)(qpA + 32);
  const bf16x8 qA3 = *(const bf16x8*)(qpA + 48);
  const u16* qpB = Qb + (size_t)(bT + q0B + q) * 64 + 8 * hi;
  const bf16x8 qB0 = *(const bf16x8*)(qpB);
  const bf16x8 qB1 = *(const bf16x8*)(qpB + 16);
  const bf16x8 qB2 = *(const bf16x8*)(qpB + 32);
  const bf16x8 qB3 = *(const bf16x8*)(qpB + 48);

  const int nu = tB + 1;                           // union-range units

  f32x16 oA0 = {}, oA1 = {}, oB0 = {}, oB1 = {};
  float mA = -INFINITY, lA = 0.f, mB = -INFINITY, lB = 0.f;

  bf16x8 k1[4], v1[4], k2[4], v2[4];

  auto loadKV = [&](bf16x8 (&kf)[4], bf16x8 (&vf)[4], int u) {
    const int k0 = bT + u * 32;
    const u16* kp = Kb + (size_t)(k0 + q) * 64 + 8 * hi;
#pragma unroll
    for (int kc = 0; kc < 4; ++kc) kf[kc] = *(const bf16x8*)(kp + kc * 16);
    const u16* vbase = Vt + (size_t)(b * 128 + u) * 2048;   // 4KB contiguous tile
#pragma unroll
    for (int dt = 0; dt < 2; ++dt)
#pragma unroll
      for (int c = 0; c < 2; ++c)
        vf[dt * 2 + c] = *(const bf16x8*)(vbase + (dt * 32 + q) * 32 + c * 16 + 8 * hi);
  };

  auto step = [&](bf16x8 (&kf)[4], bf16x8 (&vf)[4], int u, int tdiag,
                  const bf16x8& qf0, const bf16x8& qf1, const bf16x8& qf2, const bf16x8& qf3,
                  float& m, float& lsum, f32x16& o0, f32x16& o1) {
    f32x16 sc = {};
    __builtin_amdgcn_s_setprio(1);
    sc = MFMA32(kf[0], qf0, sc, 0, 0, 0);
    sc = MFMA32(kf[1], qf1, sc, 0, 0, 0);
    sc = MFMA32(kf[2], qf2, sc, 0, 0, 0);
    sc = MFMA32(kf[3], qf3, sc, 0, 0, 0);
    __builtin_amdgcn_s_setprio(0);

    if (u == tdiag) {                              // diagonal unit: causal mask
#pragma unroll
      for (int r = 0; r < 16; ++r) {
        const int key = (r & 3) + 8 * (r >> 2) + 4 * hi;
        if (key > q) sc[r] = -INFINITY;
      }
    }

    // ---- row max: pairwise tree (depth 4) + one cross-half shfl
    float t8[8];
#pragma unroll
    for (int r = 0; r < 8; ++r) t8[r] = fmaxf(sc[r], sc[r + 8]);
    float t4a = fmaxf(t8[0], t8[1]), t4b = fmaxf(t8[2], t8[3]);
    float t4c = fmaxf(t8[4], t8[5]), t4d = fmaxf(t8[6], t8[7]);
    float pm = fmaxf(fmaxf(t4a, t4b), fmaxf(t4c, t4d));
    pm = fmaxf(pm, xhalf(pm));

    // ---- defer-max rescale (T13, THR=8 in base-2 units); guarded exp2
    if (!__all(pm <= m + 8.f)) {
      const float mn = fmaxf(m, pm);
      const float al = exp2f(fmaxf(m - mn, -80.f));
#pragma unroll
      for (int r = 0; r < 16; ++r) { o0[r] *= al; o1[r] *= al; }
      lsum *= al;
      m = mn;
    }

    // ---- P = exp2(S - m), pairwise-tree row sum
    float p[16];
#pragma unroll
    for (int r = 0; r < 16; ++r) p[r] = exp2f(sc[r] - m);
    float s8[8];
#pragma unroll
    for (int r = 0; r < 8; ++r) s8[r] = p[r] + p[r + 8];
    float s4a = s8[0] + s8[1], s4b = s8[2] + s8[3];
    float s4c = s8[4] + s8[5], s4d = s8[6] + s8[7];
    float rs = (s4a + s4b) + (s4c + s4d);
    rs += xhalf(rs);
    lsum += rs;

    // ---- P -> PV B-frags: cvtpk + shfl + half-select
    u32 wl0 = cvtpk(p[0], p[1]),  wl1 = cvtpk(p[2], p[3]);
    u32 wh0 = cvtpk(p[4], p[5]),  wh1 = cvtpk(p[6], p[7]);
    u32 yl0 = cvtpk(p[8], p[9]),  yl1 = cvtpk(p[10], p[11]);
    u32 yh0 = cvtpk(p[12], p[13]), yh1 = cvtpk(p[14], p[15]);
    u32 sl0 = xhalfu(wl0), sl1 = xhalfu(wl1);
    u32 sh0 = xhalfu(wh0), sh1 = xhalfu(wh1);
    u32 tl0 = xhalfu(yl0), tl1 = xhalfu(yl1);
    u32 th0 = xhalfu(yh0), th1 = xhalfu(yh1);
    union { u32 w4[4]; bf16x8 v; } pf0, pf1;
    pf0.w4[0] = isHi ? sh0 : wl0;
    pf0.w4[1] = isHi ? sh1 : wl1;
    pf0.w4[2] = isHi ? wh0 : sl0;
    pf0.w4[3] = isHi ? wh1 : sl1;
    pf1.w4[0] = isHi ? th0 : yl0;
    pf1.w4[1] = isHi ? th1 : yl1;
    pf1.w4[2] = isHi ? yh0 : tl0;
    pf1.w4[3] = isHi ? yh1 : tl1;

    __builtin_amdgcn_s_setprio(1);
    o0 = MFMA32(vf[0], pf0.v, o0, 0, 0, 0);
    o0 = MFMA32(vf[1], pf1.v, o0, 0, 0, 0);
    o1 = MFMA32(vf[2], pf0.v, o1, 0, 0, 0);
    o1 = MFMA32(vf[3], pf1.v, o1, 0, 0, 0);
    __builtin_amdgcn_s_setprio(0);
  };

  auto computeU = [&](bf16x8 (&kf)[4], bf16x8 (&vf)[4], int u) {
    if (u <= tA) step(kf, vf, u, tA, qA0, qA1, qA2, qA3, mA, lA, oA0, oA1);
    step(kf, vf, u, tB, qB0, qB1, qB2, qB3, mB, lB, oB0, oB1);
  };

  // strided main loop: wave w handles units w, w+8, ...; 2-deep register pipeline
  int u = w;
  if (u < nu) loadKV(k1, v1, u);
#pragma unroll 1
  while (u < nu) {
    if (u + 8 < nu) loadKV(k2, v2, u + 8);
    computeU(k1, v1, u);
    u += 8;
    if (u >= nu) break;
    if (u + 8 < nu) loadKV(k1, v1, u + 8);
    computeU(k2, v2, u);
    u += 8;
  }

  // ---- two passes (tile A, tile B): hierarchical 8 -> 4 -> 1 combine
#pragma unroll 1
  for (int pass = 0; pass < 2; ++pass) {
    float m = pass ? mB : mA, lsum = pass ? lB : lA;
    f32x16 o0 = pass ? oB0 : oA0, o1 = pass ? oB1 : oA1;
    const int q0 = pass ? q0B : q0A;

    auto publish = [&](int slot) {
      float* dst = &shC[slot][l][0];
      dst[0] = m; dst[1] = lsum;
#pragma unroll
      for (int r = 0; r < 16; ++r) { dst[2 + r] = o0[r]; dst[18 + r] = o1[r]; }
    };
    auto merge = [&](int slot) {
      const float* src = &shC[slot][l][0];
      const float pm = src[0], pl = src[1];
      const float mn = fmaxf(m, pm);
      const float aS = exp2f(fmaxf(m - mn, -80.f));   // NaN(-inf - -inf) guard
      const float aP = exp2f(fmaxf(pm - mn, -80.f));
      m = mn;
      lsum = lsum * aS + pl * aP;
#pragma unroll
      for (int r = 0; r < 16; ++r) {
        o0[r] = o0[r] * aS + src[2 + r] * aP;
        o1[r] = o1[r] * aS + src[18 + r] * aP;
      }
    };

    if (w >= 4) publish(w - 4);
    __syncthreads();
    if (w < 4) merge(w);
    __syncthreads();
    if (w >= 1 && w < 4) publish(w - 1);
    __syncthreads();
    if (w == 0) {
      merge(0); merge(1); merge(2);
      const float inv = 1.0f / lsum;
#pragma unroll
      for (int r = 0; r < 16; ++r) {
        const int d = (r & 3) + 8 * (r >> 2) + 4 * hi;
        shT[q][d] = o0[r] * inv;
        shT[q][32 + d] = o1[r] * inv;
      }
      __asm volatile("s_waitcnt lgkmcnt(0)" ::: "memory");  // same-wave LDS RAW
#pragma unroll
      for (int it = 0; it < 8; ++it) {
        const int row = it * 4 + (l >> 4);
        const int c4 = (l & 15) * 4;
        float4 v = *(const float4*)&shT[row][c4];
        *(float4*)(out + (size_t)(bT + q0 + row) * 64 + c4) = v;
      }
    }
    __syncthreads();
  }
}

extern "C" void kernel_launch(void* const* d_in, const int* in_sizes, int n_in,
                              void* d_out, int out_size, void* d_ws, size_t ws_size,
                              hipStream_t stream) {
  const float* x  = (const float*)d_in[0];
  const float* Wq = (const float*)d_in[1];
  const float* Wk = (const float*)d_in[2];
  const float* Wv = (const float*)d_in[3];
  float* out = (float*)d_out;

  char* ws = (char*)d_ws;
  u16* Wt = (u16*)ws;                                   // 192*1024*2   = 384 KiB
  u16* Qb = (u16*)(ws + 393216);                        // 16384*64*2   = 2 MiB
  u16* Kb = (u16*)(ws + 393216 + 2097152);
  u16* Vt = (u16*)(ws + 393216 + 2 * 2097152);          // unit-tiled V^T [512][64][32]

  wt_kernel<<<192, 256, 0, stream>>>(Wq, Wk, Wv, Wt);
  qkv6<<<512, 256, 0, stream>>>(x, Wt, Qb, Kb, Vt);
  attn13<<<256, 512, 0, stream>>>(Qb, Kb, Vt, out);
}

// Round 21
// 74.628 us; speedup vs baseline: 1.0529x; 1.0529x over previous
//
#include <hip/hip_runtime.h>

typedef short bf16x8 __attribute__((ext_vector_type(8)));
typedef float f32x4 __attribute__((ext_vector_type(4)));
typedef float f32x16 __attribute__((ext_vector_type(16)));
typedef unsigned short u16;
typedef unsigned int u32;
typedef unsigned int u32x2 __attribute__((ext_vector_type(2)));

#define MFMA_BF16 __builtin_amdgcn_mfma_f32_16x16x32_bf16
#define MFMA32 __builtin_amdgcn_mfma_f32_32x32x16_bf16

static __device__ __forceinline__ u16 f2bf(float f) {
  union { float f; unsigned u; } v; v.f = f;
  return (u16)((v.u + 0x7FFFu + ((v.u >> 16) & 1u)) >> 16);  // RNE
}
static __device__ __forceinline__ u32 cvtpk(float lo, float hi) {
  u32 r;
  asm("v_cvt_pk_bf16_f32 %0, %1, %2" : "=v"(r) : "v"(lo), "v"(hi));
  return r;  // lo -> bits[15:0], hi -> bits[31:16]
}
static __device__ __forceinline__ bf16x8 cvt8(uint4 p, uint4 q) {  // 8 fp32 (raw bits) -> bf16x8
  union { u32 w[4]; bf16x8 b; } r;
  r.w[0] = cvtpk(__uint_as_float(p.x), __uint_as_float(p.y));
  r.w[1] = cvtpk(__uint_as_float(p.z), __uint_as_float(p.w));
  r.w[2] = cvtpk(__uint_as_float(q.x), __uint_as_float(q.y));
  r.w[3] = cvtpk(__uint_as_float(q.z), __uint_as_float(q.w));
  return r.b;
}
// VALU cross-half partner exchange: r[0]={a.lo,b.lo}, r[1]={a.hi,b.hi}
static __device__ __forceinline__ float plpartner(float x, bool isHi) {
  u32x2 r = __builtin_amdgcn_permlane32_swap(__float_as_uint(x), __float_as_uint(x), false, false);
  return __uint_as_float(isHi ? r[0] : r[1]);
}

// async global -> LDS, 16B per lane; LDS dest = wave-uniform base + lane*16
static __device__ __forceinline__ void gload16(const void* g, void* l) {
  __builtin_amdgcn_global_load_lds(
      (const __attribute__((address_space(1))) u32*)g,
      (__attribute__((address_space(3))) u32*)l, 16, 0, 0);
}

// ---------------- Kernel 0: W -> Wt[192][1024] bf16; Q gets 1/sqrt(64)*log2(e) folded in
__global__ __launch_bounds__(256) void wt_kernel(const float* __restrict__ Wq,
                                                 const float* __restrict__ Wk,
                                                 const float* __restrict__ Wv,
                                                 u16* __restrict__ Wt) {
  const int nrow = blockIdx.x;               // 0..191
  const int m = nrow >> 6, n = nrow & 63;
  const float* W = (m == 0) ? Wq : ((m == 1) ? Wk : Wv);
  const float s = (m == 0) ? 0.125f * 1.44269504f : 1.0f;  // scores in base-2 units
  for (int k = threadIdx.x; k < 1024; k += 256)
    Wt[(size_t)nrow * 1024 + k] = f2bf(W[(size_t)k * 64 + n] * s);
}

// ---------------- Kernel 1: QKV projection via global_load_lds (qkv6, proven ~30us).
// V is written UNIT-TILED: Vt[tile = tok/32][d = 0..63][key_in_unit = 0..31]
__global__ __launch_bounds__(256) void qkv6(const float* __restrict__ x,
                                            const u16* __restrict__ Wt,
                                            u16* __restrict__ Qb,
                                            u16* __restrict__ Kb,
                                            u16* __restrict__ Vt) {
  __shared__ __align__(16) char sh[2][32 * 1024];
  const int w = threadIdx.x >> 6, l = threadIdx.x & 63;
  const int lane16 = l & 15, laneHi = l >> 4;
  const int r0 = blockIdx.x * 32;
  const int nt0 = w * 3;

  const f32x4 fzero = {0.f, 0.f, 0.f, 0.f};
  f32x4 acc0 = fzero, acc1 = fzero, acc2 = fzero;   // m0 x {nt0,nt0+1,nt0+2}
  f32x4 acc3 = fzero, acc4 = fzero, acc5 = fzero;   // m1 x {nt0,nt0+1,nt0+2}

  auto stage = [&](int buf, int s) {
    char* base = &sh[buf][0];
    const int k0 = s * 64;
    if (w < 3) {
#pragma unroll
      for (int ii = 0; ii < 8; ++ii) {
        const int nt = w * 4 + (ii >> 1), kh = ii & 1;
        const u16* g = Wt + (size_t)(nt * 16 + lane16) * 1024 + k0 + kh * 32 + laneHi * 8;
        gload16(g, base + (nt * 2 + kh) * 1024);
      }
    } else {
#pragma unroll
      for (int ii = 0; ii < 8; ++ii) {
        const int m = ii >> 2, kh = (ii >> 1) & 1, p = ii & 1;
        const float* g = x + (size_t)(r0 + m * 16 + lane16) * 1024 + k0 + kh * 32 + laneHi * 8 + p * 4;
        gload16(g, base + (24 + ii) * 1024);
      }
    }
  };

  auto comp = [&](int buf) {
    const char* base = &sh[buf][0] + (size_t)l * 16;
    bf16x8 b00 = *(const bf16x8*)(base + ((nt0 + 0) * 2 + 0) * 1024);
    bf16x8 b01 = *(const bf16x8*)(base + ((nt0 + 0) * 2 + 1) * 1024);
    bf16x8 b10 = *(const bf16x8*)(base + ((nt0 + 1) * 2 + 0) * 1024);
    bf16x8 b11 = *(const bf16x8*)(base + ((nt0 + 1) * 2 + 1) * 1024);
    bf16x8 b20 = *(const bf16x8*)(base + ((nt0 + 2) * 2 + 0) * 1024);
    bf16x8 b21 = *(const bf16x8*)(base + ((nt0 + 2) * 2 + 1) * 1024);
    uint4 x00a = *(const uint4*)(base + 24 * 1024);
    uint4 x00b = *(const uint4*)(base + 25 * 1024);
    uint4 x01a = *(const uint4*)(base + 26 * 1024);
    uint4 x01b = *(const uint4*)(base + 27 * 1024);
    uint4 x10a = *(const uint4*)(base + 28 * 1024);
    uint4 x10b = *(const uint4*)(base + 29 * 1024);
    uint4 x11a = *(const uint4*)(base + 30 * 1024);
    uint4 x11b = *(const uint4*)(base + 31 * 1024);
    bf16x8 a00 = cvt8(x00a, x00b);   // m0, k 0-31 slice
    bf16x8 a01 = cvt8(x01a, x01b);   // m0, k 32-63
    bf16x8 a10 = cvt8(x10a, x10b);   // m1, k 0-31
    bf16x8 a11 = cvt8(x11a, x11b);   // m1, k 32-63
    acc0 = MFMA_BF16(a00, b00, acc0, 0, 0, 0);
    acc0 = MFMA_BF16(a01, b01, acc0, 0, 0, 0);
    acc1 = MFMA_BF16(a00, b10, acc1, 0, 0, 0);
    acc1 = MFMA_BF16(a01, b11, acc1, 0, 0, 0);
    acc2 = MFMA_BF16(a00, b20, acc2, 0, 0, 0);
    acc2 = MFMA_BF16(a01, b21, acc2, 0, 0, 0);
    acc3 = MFMA_BF16(a10, b00, acc3, 0, 0, 0);
    acc3 = MFMA_BF16(a11, b01, acc3, 0, 0, 0);
    acc4 = MFMA_BF16(a10, b10, acc4, 0, 0, 0);
    acc4 = MFMA_BF16(a11, b11, acc4, 0, 0, 0);
    acc5 = MFMA_BF16(a10, b20, acc5, 0, 0, 0);
    acc5 = MFMA_BF16(a11, b21, acc5, 0, 0, 0);
  };

  stage(0, 0);
  __syncthreads();
#pragma unroll 1
  for (int s = 0; s < 16; ++s) {
    if (s + 1 < 16) stage((s + 1) & 1, s + 1);   // async prefetch, no VGPR cost
    comp(s & 1);
    __syncthreads();                              // drains vmcnt; buf swap safe
  }

#define ST(AC, m, i)                                                        \
  {                                                                         \
    const int nt = nt0 + (i);                                               \
    if (nt < 4) {                                                           \
      _Pragma("unroll")                                                     \
      for (int r = 0; r < 4; ++r)                                           \
        Qb[(size_t)(r0 + (m) * 16 + laneHi * 4 + r) * 64 + nt * 16 + lane16] = f2bf(AC[r]); \
    } else if (nt < 8) {                                                    \
      _Pragma("unroll")                                                     \
      for (int r = 0; r < 4; ++r)                                           \
        Kb[(size_t)(r0 + (m) * 16 + laneHi * 4 + r) * 64 + (nt - 4) * 16 + lane16] = f2bf(AC[r]); \
    } else {                                                                \
      const int d = (nt - 8) * 16 + lane16;                                 \
      uint2 v;                                                              \
      v.x = cvtpk(AC[0], AC[1]);                                            \
      v.y = cvtpk(AC[2], AC[3]);                                            \
      *(uint2*)(Vt + ((size_t)(r0 >> 5) * 64 + d) * 32 + (m) * 16 + laneHi * 4) = v; \
    }                                                                       \
  }

  ST(acc0, 0, 0) ST(acc1, 0, 1) ST(acc2, 0, 2)
  ST(acc3, 1, 0) ST(acc4, 1, 1) ST(acc5, 1, 2)
}

// ---------------- Kernel 2: attn9 core with the DS-chain removed.
// All cross-lane ops (max/sum partner exchange, P-fragment redistribution) now use
// v_permlane32_swap (VALU pipe) instead of __shfl_xor (ds_bpermute + lgkm wait):
// 10 DS ops/step -> 0. swap(wl,wh) yields BOTH pf words: {wl.lo,wh.lo},{wl.hi,wh.hi}.
__global__ __launch_bounds__(256) void attn14(const u16* __restrict__ Qb,
                                              const u16* __restrict__ Kb,
                                              const u16* __restrict__ Vt,
                                              float* __restrict__ out) {
  __shared__ float shC[3][64][37];                 // waves 1..3 partials
  __shared__ __align__(16) float shT[32][68];      // output transpose staging

  const int tid = threadIdx.x, w = tid >> 6, l = tid & 63;
  const int q = l & 31, hi = l >> 5;
  const bool isHi = hi != 0;
  const int b = (blockIdx.x & 7) >> 1;             // XCD-batch affinity
  const int j = ((blockIdx.x >> 3) << 1) | (blockIdx.x & 1);   // 0..127
  const int t = (j >> 6) ? (j & 63) : (127 - (j & 63));
  const int q0 = t * 32, bT = b * 4096;

  // Q fragments (B-operand: col=q, k=d), resident
  const u16* qp = Qb + (size_t)(bT + q0 + q) * 64 + 8 * hi;
  const bf16x8 qf0 = *(const bf16x8*)(qp);
  const bf16x8 qf1 = *(const bf16x8*)(qp + 16);
  const bf16x8 qf2 = *(const bf16x8*)(qp + 32);
  const bf16x8 qf3 = *(const bf16x8*)(qp + 48);

  const int nu = t + 1;                            // 32-key units in causal range
  const int s = (nu * w) >> 2, e = (nu * (w + 1)) >> 2;

  f32x16 o0 = {}, o1 = {};                         // O^T: col=q, rows=d (2 d-tiles)
  float m = -INFINITY, lsum = 0.f;

  bf16x8 kA[4], vA[4], kB[4], vB[4];

  auto loadKV = [&](bf16x8 (&kf)[4], bf16x8 (&vf)[4], int u) {
    const int k0 = bT + u * 32;
    const u16* kp = Kb + (size_t)(k0 + q) * 64 + 8 * hi;
#pragma unroll
    for (int kc = 0; kc < 4; ++kc) kf[kc] = *(const bf16x8*)(kp + kc * 16);
    const u16* vbase = Vt + (size_t)(b * 128 + u) * 2048;   // 4KB contiguous tile
#pragma unroll
    for (int dt = 0; dt < 2; ++dt)
#pragma unroll
      for (int c = 0; c < 2; ++c)
        vf[dt * 2 + c] = *(const bf16x8*)(vbase + (dt * 32 + q) * 32 + c * 16 + 8 * hi);
  };

  auto compute = [&](bf16x8 (&kf)[4], bf16x8 (&vf)[4], int u) {
    // ---- S^T = K Q (rows=keys, cols=q)
    f32x16 sc = {};
    __builtin_amdgcn_s_setprio(1);
    sc = MFMA32(kf[0], qf0, sc, 0, 0, 0);
    sc = MFMA32(kf[1], qf1, sc, 0, 0, 0);
    sc = MFMA32(kf[2], qf2, sc, 0, 0, 0);
    sc = MFMA32(kf[3], qf3, sc, 0, 0, 0);
    __builtin_amdgcn_s_setprio(0);

    if (u == t) {                                  // diagonal unit: causal mask
#pragma unroll
      for (int r = 0; r < 16; ++r) {
        const int key = (r & 3) + 8 * (r >> 2) + 4 * hi;
        if (key > q) sc[r] = -INFINITY;
      }
    }

    // ---- row max: lane-local 16 + one VALU cross-half swap
    float pm = sc[0];
#pragma unroll
    for (int r = 1; r < 16; ++r) pm = fmaxf(pm, sc[r]);
    pm = fmaxf(pm, plpartner(pm, isHi));

    // ---- defer-max rescale (T13, THR=8 in base-2 units); guarded exp2
    if (!__all(pm <= m + 8.f)) {
      const float mn = fmaxf(m, pm);
      const float al = exp2f(fmaxf(m - mn, -80.f));   // guard -inf - -inf
#pragma unroll
      for (int r = 0; r < 16; ++r) { o0[r] *= al; o1[r] *= al; }
      lsum *= al;
      m = mn;
    }

    // ---- P = exp2(S - m), row sum (VALU cross-half swap)
    float p[16];
    float rs = 0.f;
#pragma unroll
    for (int r = 0; r < 16; ++r) { p[r] = exp2f(sc[r] - m); rs += p[r]; }
    rs += plpartner(rs, isHi);
    lsum += rs;

    // ---- P -> PV B-frags: 8 cvtpk + 4 permlane32_swap (each swap fills 2 words)
    u32 wl0 = cvtpk(p[0], p[1]),  wl1 = cvtpk(p[2], p[3]);
    u32 wh0 = cvtpk(p[4], p[5]),  wh1 = cvtpk(p[6], p[7]);
    u32 yl0 = cvtpk(p[8], p[9]),  yl1 = cvtpk(p[10], p[11]);
    u32 yh0 = cvtpk(p[12], p[13]), yh1 = cvtpk(p[14], p[15]);
    u32x2 s0 = __builtin_amdgcn_permlane32_swap(wl0, wh0, false, false);
    u32x2 s1 = __builtin_amdgcn_permlane32_swap(wl1, wh1, false, false);
    u32x2 s2 = __builtin_amdgcn_permlane32_swap(yl0, yh0, false, false);
    u32x2 s3 = __builtin_amdgcn_permlane32_swap(yl1, yh1, false, false);
    union { u32 w4[4]; bf16x8 v; } pf0, pf1;
    pf0.w4[0] = s0[0];   // {wl0.lo, wh0.lo}: keys 8hi+0,1
    pf0.w4[1] = s1[0];   // keys 8hi+2,3
    pf0.w4[2] = s0[1];   // {wl0.hi, wh0.hi}: keys 8hi+4,5
    pf0.w4[3] = s1[1];   // keys 8hi+6,7
    pf1.w4[0] = s2[0];
    pf1.w4[1] = s3[0];
    pf1.w4[2] = s2[1];
    pf1.w4[3] = s3[1];

    // ---- O^T += V^T P (rows=d, cols=q)
    __builtin_amdgcn_s_setprio(1);
    o0 = MFMA32(vf[0], pf0.v, o0, 0, 0, 0);
    o0 = MFMA32(vf[1], pf1.v, o0, 0, 0, 0);
    o1 = MFMA32(vf[2], pf0.v, o1, 0, 0, 0);
    o1 = MFMA32(vf[3], pf1.v, o1, 0, 0, 0);
    __builtin_amdgcn_s_setprio(0);
  };

  // main loop: 2x unrolled, double-buffered K/V fragments (proven structure)
  int u = s;
  if (u < e) loadKV(kA, vA, u);
#pragma unroll 1
  while (u < e) {
    if (u + 1 < e) loadKV(kB, vB, u + 1);
    compute(kA, vA, u);
    ++u;
    if (u >= e) break;
    if (u + 1 < e) loadKV(kA, vA, u + 1);
    compute(kB, vB, u);
    ++u;
  }

  // ---- combine: waves 1..3 publish, wave 0 merges
  if (w > 0) {
    float* dst = &shC[w - 1][l][0];
    dst[0] = m; dst[1] = lsum;
#pragma unroll
    for (int r = 0; r < 16; ++r) { dst[2 + r] = o0[r]; dst[18 + r] = o1[r]; }
  }
  __syncthreads();
  if (w == 0) {
#pragma unroll
    for (int peer = 0; peer < 3; ++peer) {
      const float* src = &shC[peer][l][0];
      const float pm = src[0], pl = src[1];
      const float mn = fmaxf(m, pm);
      const float aS = exp2f(fmaxf(m - mn, -80.f));   // NaN(-inf - -inf) -> -80 guard
      const float aP = exp2f(fmaxf(pm - mn, -80.f));
      m = mn;
      lsum = lsum * aS + pl * aP;
#pragma unroll
      for (int r = 0; r < 16; ++r) {
        o0[r] = o0[r] * aS + src[2 + r] * aP;
        o1[r] = o1[r] * aS + src[18 + r] * aP;
      }
    }
    const float inv = 1.0f / lsum;
    // stage O (rows=q, cols=d) into LDS for coalesced output
#pragma unroll
    for (int r = 0; r < 16; ++r) {
      const int d = (r & 3) + 8 * (r >> 2) + 4 * hi;
      shT[q][d] = o0[r] * inv;
      shT[q][32 + d] = o1[r] * inv;
    }
    __asm volatile("s_waitcnt lgkmcnt(0)" ::: "memory");  // same-wave LDS RAW
#pragma unroll
    for (int it = 0; it < 8; ++it) {
      const int row = it * 4 + (l >> 4);
      const int c4 = (l & 15) * 4;
      float4 v = *(const float4*)&shT[row][c4];
      *(float4*)(out + (size_t)(bT + q0 + row) * 64 + c4) = v;
    }
  }
}

extern "C" void kernel_launch(void* const* d_in, const int* in_sizes, int n_in,
                              void* d_out, int out_size, void* d_ws, size_t ws_size,
                              hipStream_t stream) {
  const float* x  = (const float*)d_in[0];
  const float* Wq = (const float*)d_in[1];
  const float* Wk = (const float*)d_in[2];
  const float* Wv = (const float*)d_in[3];
  float* out = (float*)d_out;

  char* ws = (char*)d_ws;
  u16* Wt = (u16*)ws;                                   // 192*1024*2   = 384 KiB
  u16* Qb = (u16*)(ws + 393216);                        // 16384*64*2   = 2 MiB
  u16* Kb = (u16*)(ws + 393216 + 2097152);
  u16* Vt = (u16*)(ws + 393216 + 2 * 2097152);          // unit-tiled V^T [512][64][32]

  wt_kernel<<<192, 256, 0, stream>>>(Wq, Wk, Wv, Wt);
  qkv6<<<512, 256, 0, stream>>>(x, Wt, Qb, Kb, Vt);
  attn14<<<512, 256, 0, stream>>>(Qb, Kb, Vt, out);
}